// Round 8
// baseline (328.902 us; speedup 1.0000x reference)
//
#include <hip/hip_runtime.h>
#include <hip/hip_bf16.h>

#define TDIM 2048
#define BDIM 4
#define CDIM 1024
#define HDIM 16
#define DH   64

typedef __hip_bfloat16 bf16;
typedef __attribute__((ext_vector_type(8))) short bf16x8;
typedef __attribute__((ext_vector_type(4))) short bf16x4;
typedef __attribute__((ext_vector_type(4))) float f32x4;

// async global->LDS, 16B per lane; LDS dest = wave-uniform base + lane*16
__device__ __forceinline__ void async_ld16(const bf16* g, bf16* l) {
    __builtin_amdgcn_global_load_lds(
        (const __attribute__((address_space(1))) unsigned int*)g,
        (__attribute__((address_space(3))) unsigned int*)l, 16, 0, 0);
}

__device__ __forceinline__ unsigned short bf16bits(float x) {
    bf16 b = __float2bfloat16(x);
    return *(unsigned short*)&b;
}

// 16x16x16 bf16 MFMA (k=16): builtin name varies; asm fallback is ISA-verified
__device__ __forceinline__ f32x4 mfma_16x16x16_bf16(bf16x4 a, bf16x4 b, f32x4 c) {
#if __has_builtin(__builtin_amdgcn_mfma_f32_16x16x16_bf16)
    return __builtin_amdgcn_mfma_f32_16x16x16_bf16(a, b, c, 0, 0, 0);
#elif __has_builtin(__builtin_amdgcn_mfma_f32_16x16x16bf16_1k)
    return __builtin_amdgcn_mfma_f32_16x16x16bf16_1k(a, b, c, 0, 0, 0);
#else
    asm volatile("v_mfma_f32_16x16x16_bf16 %0, %1, %2, %0"
                 : "+v"(c) : "v"(a), "v"(b));
    return c;
#endif
}

// ---------------------------------------------------------------------------
__global__ void convert_x4(const float4* __restrict__ src, ushort4* __restrict__ dst, int n4) {
    int i = blockIdx.x * blockDim.x + threadIdx.x;
    if (i >= n4) return;
    float4 v = src[i];
    ushort4 o;
    o.x = bf16bits(v.x); o.y = bf16bits(v.y);
    o.z = bf16bits(v.z); o.w = bf16bits(v.w);
    dst[i] = o;
}

__global__ void convert_biases(const float* __restrict__ b0, const float* __restrict__ b1,
                               const float* __restrict__ b2, const float* __restrict__ b3,
                               bf16* __restrict__ dst) {
    int i = blockIdx.x * blockDim.x + threadIdx.x;   // 0..4095
    int which = i >> 10, j = i & 1023;
    const float* src = (which == 0) ? b0 : (which == 1) ? b1 : (which == 2) ? b2 : b3;
    dst[i] = __float2bfloat16(src[j]);
}

// ---------------------------------------------------------------------------
// LDS-tiled transpose, fused over Wq/Wk/Wv: z = which*16 + h.
// ---------------------------------------------------------------------------
__global__ __launch_bounds__(256) void transpose_qkv_kernel(
    const float* __restrict__ Wq, const float* __restrict__ Wk, const float* __restrict__ Wv,
    bf16* __restrict__ WqT, bf16* __restrict__ WkT, bf16* __restrict__ WvT) {
    __shared__ float tile[64][65];
    const int which = blockIdx.z >> 4, h = blockIdx.z & 15;
    const float* W  = ((which == 0) ? Wq  : (which == 1) ? Wk  : Wv)  + (size_t)h * CDIM * DH;
    bf16*        WT = ((which == 0) ? WqT : (which == 1) ? WkT : WvT) + (size_t)h * CDIM * DH;
    const int c0 = blockIdx.x * 64;
    for (int it = 0; it < 16; it++) {
        int e = it * 256 + threadIdx.x;
        int r = e >> 6, col = e & 63;
        tile[r][col] = W[(size_t)(c0 + r) * DH + col];
    }
    __syncthreads();
    for (int it = 0; it < 16; it++) {
        int e = it * 256 + threadIdx.x;
        int r = e >> 6, col = e & 63;
        WT[(size_t)r * CDIM + c0 + col] = __float2bfloat16(tile[col][r]);
    }
}

__global__ __launch_bounds__(256) void transpose_wo_kernel(
    const float* __restrict__ W, bf16* __restrict__ WT) {
    __shared__ float tile[64][65];
    const int c0 = blockIdx.x * 64, d0 = blockIdx.y * 64;
    for (int it = 0; it < 16; it++) {
        int e = it * 256 + threadIdx.x;
        int r = e >> 6, col = e & 63;
        tile[r][col] = W[(size_t)(c0 + r) * CDIM + d0 + col];
    }
    __syncthreads();
    for (int it = 0; it < 16; it++) {
        int e = it * 256 + threadIdx.x;
        int r = e >> 6, col = e & 63;
        WT[(size_t)(d0 + r) * CDIM + c0 + col] = __float2bfloat16(tile[col][r]);
    }
}

// V [bh][t][d] -> Vt [bh][d][t], 64x64 bf16 tiles
__global__ __launch_bounds__(256) void transpose_v_kernel(
    const bf16* __restrict__ V, bf16* __restrict__ Vt) {
    __shared__ unsigned short tile[64][65];
    const int bh = blockIdx.y, t0 = blockIdx.x * 64;
    const unsigned short* Vp  = (const unsigned short*)V + ((size_t)bh * TDIM + t0) * DH;
    unsigned short*       Vtp = (unsigned short*)Vt + (size_t)bh * DH * TDIM;
    for (int it = 0; it < 16; it++) {
        int e = it * 256 + threadIdx.x;
        int r = e >> 6, c = e & 63;
        tile[r][c] = Vp[(size_t)r * DH + c];
    }
    __syncthreads();
    for (int it = 0; it < 16; it++) {
        int e = it * 256 + threadIdx.x;
        int r = e >> 6, c = e & 63;
        Vtp[(size_t)r * TDIM + t0 + c] = tile[c][r];
    }
}

// ---------------------------------------------------------------------------
// 128x128 MFMA GEMM with global_load_lds staging (m97 pattern).
// QKV variant: z selects weight/bias/output; Q pre-scaled by 1/32.
// ---------------------------------------------------------------------------
__global__ __launch_bounds__(256) void proj_qkv_kernel(
    const bf16* __restrict__ X,
    const bf16* __restrict__ WqT, const bf16* __restrict__ WkT, const bf16* __restrict__ WvT,
    const bf16* __restrict__ bq,  const bf16* __restrict__ bk,  const bf16* __restrict__ bvv,
    bf16* __restrict__ Qo, bf16* __restrict__ Ko, bf16* __restrict__ Vo)
{
    const int z = blockIdx.z;
    const bf16* Bt   = (z == 0) ? WqT : (z == 1) ? WkT : WvT;
    const bf16* bias = (z == 0) ? bq  : (z == 1) ? bk  : bvv;

    __shared__ __align__(16) bf16 As[128 * 32];
    __shared__ __align__(16) bf16 Bs[128 * 32];

    const int tid  = threadIdx.x;
    const int lane = tid & 63;
    const int wave = tid >> 6;
    const int wr = wave >> 1, wc = wave & 1;
    const int l15 = lane & 15, quad = lane >> 4;

    const int blockM = blockIdx.y * 128;
    const int blockN = blockIdx.x * 128;

    f32x4 acc[4][4];
    for (int i = 0; i < 4; i++)
        for (int j = 0; j < 4; j++)
            acc[i][j] = (f32x4){0.f, 0.f, 0.f, 0.f};

    const int srow = lane >> 2, scol = (lane & 3) * 8;
    for (int k0 = 0; k0 < CDIM; k0 += 32) {
        for (int cc = 0; cc < 2; cc++) {
            int chunk = wave * 2 + cc;
            int row = chunk * 16 + srow;
            async_ld16(&X [(size_t)(blockM + row) * CDIM + k0 + scol], &As[chunk * 512]);
            async_ld16(&Bt[(size_t)(blockN + row) * CDIM + k0 + scol], &Bs[chunk * 512]);
        }
        __syncthreads();

        bf16x8 af[4], bfr[4];
        for (int mi = 0; mi < 4; mi++)
            af[mi] = *(const bf16x8*)&As[(wr * 64 + mi * 16 + l15) * 32 + quad * 8];
        for (int ni = 0; ni < 4; ni++)
            bfr[ni] = *(const bf16x8*)&Bs[(wc * 64 + ni * 16 + l15) * 32 + quad * 8];

        for (int mi = 0; mi < 4; mi++)
            for (int ni = 0; ni < 4; ni++)
                acc[mi][ni] = __builtin_amdgcn_mfma_f32_16x16x32_bf16(
                    af[mi], bfr[ni], acc[mi][ni], 0, 0, 0);
        __syncthreads();
    }

    for (int mi = 0; mi < 4; mi++) {
        int mbase = blockM + wr * 64 + mi * 16 + quad * 4;
        for (int ni = 0; ni < 4; ni++) {
            int n = blockN + wc * 64 + ni * 16 + l15;
            float bval = __bfloat162float(bias[n]);
            int h = n >> 6, d = n & 63;
            for (int r = 0; r < 4; r++) {
                int mm = mbase + r;
                int b = mm >> 11, t = mm & 2047;
                float val = acc[mi][ni][r] + bval;
                size_t idx = (((size_t)b * HDIM + h) * TDIM + t) * DH + d;
                if (z == 0)      Qo[idx] = __float2bfloat16(val * 0.03125f);
                else if (z == 1) Ko[idx] = __float2bfloat16(val);
                else             Vo[idx] = __float2bfloat16(val);
            }
        }
    }
}

// ---------------------------------------------------------------------------
// Output projection: Y[M,K] @ WoT[N,K]^T + bo -> fp32 Out
// ---------------------------------------------------------------------------
__global__ __launch_bounds__(256) void proj_out_kernel(
    const bf16* __restrict__ X, const bf16* __restrict__ Bt,
    const bf16* __restrict__ bias, float* __restrict__ Out)
{
    __shared__ __align__(16) bf16 As[128 * 32];
    __shared__ __align__(16) bf16 Bs[128 * 32];

    const int tid  = threadIdx.x;
    const int lane = tid & 63;
    const int wave = tid >> 6;
    const int wr = wave >> 1, wc = wave & 1;
    const int l15 = lane & 15, quad = lane >> 4;

    const int blockM = blockIdx.y * 128;
    const int blockN = blockIdx.x * 128;

    f32x4 acc[4][4];
    for (int i = 0; i < 4; i++)
        for (int j = 0; j < 4; j++)
            acc[i][j] = (f32x4){0.f, 0.f, 0.f, 0.f};

    const int srow = lane >> 2, scol = (lane & 3) * 8;
    for (int k0 = 0; k0 < CDIM; k0 += 32) {
        for (int cc = 0; cc < 2; cc++) {
            int chunk = wave * 2 + cc;
            int row = chunk * 16 + srow;
            async_ld16(&X [(size_t)(blockM + row) * CDIM + k0 + scol], &As[chunk * 512]);
            async_ld16(&Bt[(size_t)(blockN + row) * CDIM + k0 + scol], &Bs[chunk * 512]);
        }
        __syncthreads();

        bf16x8 af[4], bfr[4];
        for (int mi = 0; mi < 4; mi++)
            af[mi] = *(const bf16x8*)&As[(wr * 64 + mi * 16 + l15) * 32 + quad * 8];
        for (int ni = 0; ni < 4; ni++)
            bfr[ni] = *(const bf16x8*)&Bs[(wc * 64 + ni * 16 + l15) * 32 + quad * 8];

        for (int mi = 0; mi < 4; mi++)
            for (int ni = 0; ni < 4; ni++)
                acc[mi][ni] = __builtin_amdgcn_mfma_f32_16x16x32_bf16(
                    af[mi], bfr[ni], acc[mi][ni], 0, 0, 0);
        __syncthreads();
    }

    for (int mi = 0; mi < 4; mi++) {
        int mbase = blockM + wr * 64 + mi * 16 + quad * 4;
        for (int ni = 0; ni < 4; ni++) {
            int n = blockN + wc * 64 + ni * 16 + l15;
            float bval = __bfloat162float(bias[n]);
            for (int r = 0; r < 4; r++)
                Out[(size_t)(mbase + r) * CDIM + n] = acc[mi][ni][r] + bval;
        }
    }
}

// ---------------------------------------------------------------------------
// Flash attention, causal, KEY-SPLIT transposed-score formulation.
// Each wave owns 16 keys of the 64-key tile x ALL 64 q of the block's q-tile.
// S^T = K.Q^T exits QK in C-layout [key=quad*4+r][q=l15] == B-operand layout
// of 16x16x16 MFMA (k=16 keys) -> exp in registers feeds PV directly, NO LDS
// round-trip for P.  K reads 2 b128/wave/iter, V reads 4 b64/wave/iter (4x
// fewer than q-split).  Per-wave partial O^T reduced across waves in epilogue.
// ---------------------------------------------------------------------------
__global__ __launch_bounds__(256) void attn_kernel(
    const bf16* __restrict__ Q, const bf16* __restrict__ Kb,
    const bf16* __restrict__ Vt, bf16* __restrict__ Y)
{
    const int bh    = blockIdx.y;
    const int qTile = (int)gridDim.x - 1 - blockIdx.x;   // heavy first
    const int qBase = qTile * 64;
    const int tid  = threadIdx.x;
    const int lane = tid & 63, wave = tid >> 6;
    const int l15 = lane & 15, quad = lane >> 4;

    // Ks/Vs: 64x64 tiles, stride 72 (2-way bank aliasing only).  Epilogue
    // reuses this region as fp32 O-buffer [64][68] + denom [4][64].
    __shared__ __align__(16) char smem[2 * 64 * 72 * 2 + 4 * 64 * 4];
    bf16*  Ks   = (bf16*)smem;                   // [key][dh]
    bf16*  Vs   = Ks + 64 * 72;                  // [dh][key]
    float* Of   = (float*)smem;                  // [d][q] stride 68 (epilogue)
    float* dbuf = (float*)(smem + 2 * 64 * 72 * 2);   // [wave][q]

    // Q B-fragments for ALL 64 q: B[k=dh quad*8+j][n=q l15], 4 nt x 2 k-steps
    bf16x8 qf[4][2];
    for (int nt = 0; nt < 4; nt++) {
        const size_t qrow = (size_t)bh * TDIM + qBase + nt * 16 + l15;
        qf[nt][0] = *(const bf16x8*)&Q[qrow * DH + quad * 8];
        qf[nt][1] = *(const bf16x8*)&Q[qrow * DH + 32 + quad * 8];
    }

    // per-wave partial O^T: [d = mt*16+quad*4+r][q = nt*16+l15]
    f32x4 o[4][4];
    for (int i = 0; i < 4; i++)
        for (int j = 0; j < 4; j++)
            o[i][j] = (f32x4){0.f, 0.f, 0.f, 0.f};
    float lsum[4] = {0.f, 0.f, 0.f, 0.f};        // partial denom, q=nt*16+l15

    // staging coords: 256 threads x 2 chunks x 8 bf16 = 64x64 tile
    const int r0 = tid >> 3, kc0 = (tid & 7) * 8;

    const int nkt = qTile + 1;
    uint4 kreg0 = *(const uint4*)&Kb[((size_t)bh * TDIM + r0) * DH + kc0];
    uint4 kreg1 = *(const uint4*)&Kb[((size_t)bh * TDIM + r0 + 32) * DH + kc0];
    uint4 vreg0 = *(const uint4*)&Vt[((size_t)bh * DH + r0) * TDIM + kc0];
    uint4 vreg1 = *(const uint4*)&Vt[((size_t)bh * DH + r0 + 32) * TDIM + kc0];

    for (int kt = 0; kt < nkt; kt++) {
        *(uint4*)&Ks[r0 * 72 + kc0]        = kreg0;
        *(uint4*)&Ks[(r0 + 32) * 72 + kc0] = kreg1;
        *(uint4*)&Vs[r0 * 72 + kc0]        = vreg0;
        *(uint4*)&Vs[(r0 + 32) * 72 + kc0] = vreg1;
        __syncthreads();

        if (kt + 1 < nkt) {
            const int nb = (kt + 1) * 64;
            kreg0 = *(const uint4*)&Kb[((size_t)bh * TDIM + nb + r0) * DH + kc0];
            kreg1 = *(const uint4*)&Kb[((size_t)bh * TDIM + nb + r0 + 32) * DH + kc0];
            vreg0 = *(const uint4*)&Vt[((size_t)bh * DH + r0) * TDIM + nb + kc0];
            vreg1 = *(const uint4*)&Vt[((size_t)bh * DH + r0 + 32) * TDIM + nb + kc0];
        }

        // wave's K A-fragment: A[m=key wave*16+l15][k=dh quad*8+j]
        bf16x8 k0 = *(const bf16x8*)&Ks[(wave * 16 + l15) * 72 + quad * 8];
        bf16x8 k1 = *(const bf16x8*)&Ks[(wave * 16 + l15) * 72 + 32 + quad * 8];
        // wave's V A-fragments for PV: A[m=d mt*16+l15][k=key quad*4+j]
        bf16x4 vA[4];
        for (int mt = 0; mt < 4; mt++)
            vA[mt] = *(const bf16x4*)&Vs[(mt * 16 + l15) * 72 + wave * 16 + quad * 4];

        // S^T = K.Q^T over the wave's 16 keys x 64 q
        f32x4 s[4];
        for (int nt = 0; nt < 4; nt++) {
            f32x4 a = (f32x4){0.f, 0.f, 0.f, 0.f};
            a = __builtin_amdgcn_mfma_f32_16x16x32_bf16(k0, qf[nt][0], a, 0, 0, 0);
            a = __builtin_amdgcn_mfma_f32_16x16x32_bf16(k1, qf[nt][1], a, 0, 0, 0);
            s[nt] = a;   // [key = wave*16+quad*4+r][q = nt*16+l15]
        }

        // exp (max-free), causal mask on diag tile, PV directly from registers
        const bool diag = (kt == qTile);
        const int keyg = kt * 64 + wave * 16 + quad * 4;        // + r
        for (int nt = 0; nt < 4; nt++) {
            const int qg = qBase + nt * 16 + l15;
            bf16x4 pb;
            for (int r = 0; r < 4; r++) {
                float pe = __expf(s[nt][r]);
                if (diag && (keyg + r > qg)) pe = 0.f;
                lsum[nt] += pe;
                pb[r] = (short)bf16bits(pe);
            }
            for (int mt = 0; mt < 4; mt++)
                o[mt][nt] = mfma_16x16x16_bf16(vA[mt], pb, o[mt][nt]);
        }
        __syncthreads();
    }

    // ---- epilogue ----
    // denominator: reduce across quads (keys within wave), then across waves
    float dsum[4];
    for (int nt = 0; nt < 4; nt++) {
        float v = lsum[nt];
        v += __shfl_xor(v, 16, 64);
        v += __shfl_xor(v, 32, 64);
        dsum[nt] = v;
    }
    if (quad == 0)
        for (int nt = 0; nt < 4; nt++)
            dbuf[wave * 64 + nt * 16 + l15] = dsum[nt];

    // cross-wave O^T reduction into LDS (sequential adds, 4 barriers)
    for (int w = 0; w < 4; w++) {
        if (wave == w) {
            for (int mt = 0; mt < 4; mt++)
                for (int nt = 0; nt < 4; nt++)
                    for (int r = 0; r < 4; r++) {
                        int d = mt * 16 + quad * 4 + r, q = nt * 16 + l15;
                        if (w == 0) Of[d * 68 + q]  = o[mt][nt][r];
                        else        Of[d * 68 + q] += o[mt][nt][r];
                    }
        }
        __syncthreads();
    }

    // normalize + store: thread -> (q = tid>>2, 16 d's)
    const int b = bh >> 4, h = bh & 15;
    const int q = tid >> 2, dc = (tid & 3) * 16;
    const float inv = 1.0f / (dbuf[q] + dbuf[64 + q] + dbuf[128 + q] + dbuf[192 + q]);
    for (int c = 0; c < 2; c++) {
        unsigned short pk[8];
        for (int j = 0; j < 8; j++)
            pk[j] = bf16bits(Of[(dc + c * 8 + j) * 68 + q] * inv);
        *(uint4*)&Y[((size_t)b * TDIM + qBase + q) * CDIM + h * DH + dc + c * 8] =
            *(uint4*)pk;
    }
}

// ---------------------------------------------------------------------------
extern "C" void kernel_launch(void* const* d_in, const int* in_sizes, int n_in,
                              void* d_out, int out_size, void* d_ws, size_t ws_size,
                              hipStream_t stream) {
    (void)in_sizes; (void)n_in; (void)out_size; (void)ws_size;

    char* ws = (char*)d_ws;
    const size_t SZ_BHTD = (size_t)BDIM * HDIM * TDIM * DH * sizeof(bf16);  // 16 MiB
    const size_t SZ_W    = (size_t)HDIM * CDIM * DH * sizeof(bf16);         // 2 MiB
    bf16* Qb  = (bf16*)(ws);
    bf16* Kb  = (bf16*)(ws + SZ_BHTD);
    bf16* Vt  = (bf16*)(ws + 2 * SZ_BHTD);
    bf16* Y   = (bf16*)(ws + 3 * SZ_BHTD);
    bf16* WqT = (bf16*)(ws + 4 * SZ_BHTD);
    bf16* WkT = (bf16*)(ws + 4 * SZ_BHTD + SZ_W);
    bf16* WvT = (bf16*)(ws + 4 * SZ_BHTD + 2 * SZ_W);
    bf16* WoT = (bf16*)(ws + 4 * SZ_BHTD + 3 * SZ_W);
    bf16* xC  = (bf16*)(ws + 4 * SZ_BHTD + 4 * SZ_W);                       // 16 MiB
    bf16* bqC = (bf16*)(ws + 5 * SZ_BHTD + 4 * SZ_W);
    bf16* bkC = bqC + 1024;
    bf16* bvC = bqC + 2048;
    bf16* boC = bqC + 3072;
    bf16* Vb  = (bf16*)d_out;   // scratch: V [bh][t][d] lives in d_out until proj_out

    const int nX4 = (BDIM * TDIM * CDIM) / 4;
    convert_x4<<<nX4 / 256, 256, 0, stream>>>((const float4*)d_in[0], (ushort4*)xC, nX4);
    convert_biases<<<16, 256, 0, stream>>>((const float*)d_in[2], (const float*)d_in[4],
                                           (const float*)d_in[6], (const float*)d_in[8], bqC);

    transpose_qkv_kernel<<<dim3(CDIM / 64, 1, 48), 256, 0, stream>>>(
        (const float*)d_in[1], (const float*)d_in[3], (const float*)d_in[5], WqT, WkT, WvT);
    transpose_wo_kernel<<<dim3(CDIM / 64, CDIM / 64), 256, 0, stream>>>(
        (const float*)d_in[7], WoT);

    dim3 gq(CDIM / 128, (BDIM * TDIM) / 128, 3);
    proj_qkv_kernel<<<gq, 256, 0, stream>>>(xC, WqT, WkT, WvT, bqC, bkC, bvC, Qb, Kb, Vb);

    transpose_v_kernel<<<dim3(TDIM / 64, BDIM * HDIM), 256, 0, stream>>>(Vb, Vt);

    attn_kernel<<<dim3(TDIM / 64, BDIM * HDIM), 256, 0, stream>>>(Qb, Kb, Vt, Y);

    proj_out_kernel<<<dim3(CDIM / 128, (BDIM * TDIM) / 128), 256, 0, stream>>>(
        Y, WoT, boC, (float*)d_out);
}

// Round 9
// 300.169 us; speedup vs baseline: 1.0957x; 1.0957x over previous
//
#include <hip/hip_runtime.h>
#include <hip/hip_bf16.h>

#define TDIM 2048
#define BDIM 4
#define CDIM 1024
#define HDIM 16
#define DH   64

typedef __hip_bfloat16 bf16;
typedef __attribute__((ext_vector_type(8))) short bf16x8;
typedef __attribute__((ext_vector_type(4))) short bf16x4;
typedef __attribute__((ext_vector_type(4))) float f32x4;

// async global->LDS, 16B per lane; LDS dest = wave-uniform base + lane*16
__device__ __forceinline__ void async_ld16(const bf16* g, bf16* l) {
    __builtin_amdgcn_global_load_lds(
        (const __attribute__((address_space(1))) unsigned int*)g,
        (__attribute__((address_space(3))) unsigned int*)l, 16, 0, 0);
}

__device__ __forceinline__ unsigned short bf16bits(float x) {
    bf16 b = __float2bfloat16(x);
    return *(unsigned short*)&b;
}

// 16x16x16 bf16 MFMA (k=16): verified working in round 8 (passed correctness)
__device__ __forceinline__ f32x4 mfma_16x16x16_bf16(bf16x4 a, bf16x4 b, f32x4 c) {
#if __has_builtin(__builtin_amdgcn_mfma_f32_16x16x16_bf16)
    return __builtin_amdgcn_mfma_f32_16x16x16_bf16(a, b, c, 0, 0, 0);
#elif __has_builtin(__builtin_amdgcn_mfma_f32_16x16x16bf16_1k)
    return __builtin_amdgcn_mfma_f32_16x16x16bf16_1k(a, b, c, 0, 0, 0);
#else
    asm volatile("v_mfma_f32_16x16x16_bf16 %0, %1, %2, %0"
                 : "+v"(c) : "v"(a), "v"(b));
    return c;
#endif
}

// ---------------------------------------------------------------------------
__global__ void convert_x4(const float4* __restrict__ src, ushort4* __restrict__ dst, int n4) {
    int i = blockIdx.x * blockDim.x + threadIdx.x;
    if (i >= n4) return;
    float4 v = src[i];
    ushort4 o;
    o.x = bf16bits(v.x); o.y = bf16bits(v.y);
    o.z = bf16bits(v.z); o.w = bf16bits(v.w);
    dst[i] = o;
}

__global__ void convert_biases(const float* __restrict__ b0, const float* __restrict__ b1,
                               const float* __restrict__ b2, const float* __restrict__ b3,
                               bf16* __restrict__ dst) {
    int i = blockIdx.x * blockDim.x + threadIdx.x;   // 0..4095
    int which = i >> 10, j = i & 1023;
    const float* src = (which == 0) ? b0 : (which == 1) ? b1 : (which == 2) ? b2 : b3;
    dst[i] = __float2bfloat16(src[j]);
}

// ---------------------------------------------------------------------------
// LDS-tiled transpose, fused over Wq/Wk/Wv: z = which*16 + h.
// ---------------------------------------------------------------------------
__global__ __launch_bounds__(256) void transpose_qkv_kernel(
    const float* __restrict__ Wq, const float* __restrict__ Wk, const float* __restrict__ Wv,
    bf16* __restrict__ WqT, bf16* __restrict__ WkT, bf16* __restrict__ WvT) {
    __shared__ float tile[64][65];
    const int which = blockIdx.z >> 4, h = blockIdx.z & 15;
    const float* W  = ((which == 0) ? Wq  : (which == 1) ? Wk  : Wv)  + (size_t)h * CDIM * DH;
    bf16*        WT = ((which == 0) ? WqT : (which == 1) ? WkT : WvT) + (size_t)h * CDIM * DH;
    const int c0 = blockIdx.x * 64;
    for (int it = 0; it < 16; it++) {
        int e = it * 256 + threadIdx.x;
        int r = e >> 6, col = e & 63;
        tile[r][col] = W[(size_t)(c0 + r) * DH + col];
    }
    __syncthreads();
    for (int it = 0; it < 16; it++) {
        int e = it * 256 + threadIdx.x;
        int r = e >> 6, col = e & 63;
        WT[(size_t)r * CDIM + c0 + col] = __float2bfloat16(tile[col][r]);
    }
}

__global__ __launch_bounds__(256) void transpose_wo_kernel(
    const float* __restrict__ W, bf16* __restrict__ WT) {
    __shared__ float tile[64][65];
    const int c0 = blockIdx.x * 64, d0 = blockIdx.y * 64;
    for (int it = 0; it < 16; it++) {
        int e = it * 256 + threadIdx.x;
        int r = e >> 6, col = e & 63;
        tile[r][col] = W[(size_t)(c0 + r) * CDIM + d0 + col];
    }
    __syncthreads();
    for (int it = 0; it < 16; it++) {
        int e = it * 256 + threadIdx.x;
        int r = e >> 6, col = e & 63;
        WT[(size_t)(d0 + r) * CDIM + c0 + col] = __float2bfloat16(tile[col][r]);
    }
}

// V [bh][t][d] -> Vt [bh][d][t], 64x64 bf16 tiles
__global__ __launch_bounds__(256) void transpose_v_kernel(
    const bf16* __restrict__ V, bf16* __restrict__ Vt) {
    __shared__ unsigned short tile[64][65];
    const int bh = blockIdx.y, t0 = blockIdx.x * 64;
    const unsigned short* Vp  = (const unsigned short*)V + ((size_t)bh * TDIM + t0) * DH;
    unsigned short*       Vtp = (unsigned short*)Vt + (size_t)bh * DH * TDIM;
    for (int it = 0; it < 16; it++) {
        int e = it * 256 + threadIdx.x;
        int r = e >> 6, c = e & 63;
        tile[r][c] = Vp[(size_t)r * DH + c];
    }
    __syncthreads();
    for (int it = 0; it < 16; it++) {
        int e = it * 256 + threadIdx.x;
        int r = e >> 6, c = e & 63;
        Vtp[(size_t)r * TDIM + t0 + c] = tile[c][r];
    }
}

// ---------------------------------------------------------------------------
// 128x128 MFMA GEMM with global_load_lds staging (m97 pattern).
// QKV variant: z selects weight/bias/output; Q pre-scaled by 1/32.
// ---------------------------------------------------------------------------
__global__ __launch_bounds__(256) void proj_qkv_kernel(
    const bf16* __restrict__ X,
    const bf16* __restrict__ WqT, const bf16* __restrict__ WkT, const bf16* __restrict__ WvT,
    const bf16* __restrict__ bq,  const bf16* __restrict__ bk,  const bf16* __restrict__ bvv,
    bf16* __restrict__ Qo, bf16* __restrict__ Ko, bf16* __restrict__ Vo)
{
    const int z = blockIdx.z;
    const bf16* Bt   = (z == 0) ? WqT : (z == 1) ? WkT : WvT;
    const bf16* bias = (z == 0) ? bq  : (z == 1) ? bk  : bvv;

    __shared__ __align__(16) bf16 As[128 * 32];
    __shared__ __align__(16) bf16 Bs[128 * 32];

    const int tid  = threadIdx.x;
    const int lane = tid & 63;
    const int wave = tid >> 6;
    const int wr = wave >> 1, wc = wave & 1;
    const int l15 = lane & 15, quad = lane >> 4;

    const int blockM = blockIdx.y * 128;
    const int blockN = blockIdx.x * 128;

    f32x4 acc[4][4];
    for (int i = 0; i < 4; i++)
        for (int j = 0; j < 4; j++)
            acc[i][j] = (f32x4){0.f, 0.f, 0.f, 0.f};

    const int srow = lane >> 2, scol = (lane & 3) * 8;
    for (int k0 = 0; k0 < CDIM; k0 += 32) {
        for (int cc = 0; cc < 2; cc++) {
            int chunk = wave * 2 + cc;
            int row = chunk * 16 + srow;
            async_ld16(&X [(size_t)(blockM + row) * CDIM + k0 + scol], &As[chunk * 512]);
            async_ld16(&Bt[(size_t)(blockN + row) * CDIM + k0 + scol], &Bs[chunk * 512]);
        }
        __syncthreads();

        bf16x8 af[4], bfr[4];
        for (int mi = 0; mi < 4; mi++)
            af[mi] = *(const bf16x8*)&As[(wr * 64 + mi * 16 + l15) * 32 + quad * 8];
        for (int ni = 0; ni < 4; ni++)
            bfr[ni] = *(const bf16x8*)&Bs[(wc * 64 + ni * 16 + l15) * 32 + quad * 8];

        for (int mi = 0; mi < 4; mi++)
            for (int ni = 0; ni < 4; ni++)
                acc[mi][ni] = __builtin_amdgcn_mfma_f32_16x16x32_bf16(
                    af[mi], bfr[ni], acc[mi][ni], 0, 0, 0);
        __syncthreads();
    }

    for (int mi = 0; mi < 4; mi++) {
        int mbase = blockM + wr * 64 + mi * 16 + quad * 4;
        for (int ni = 0; ni < 4; ni++) {
            int n = blockN + wc * 64 + ni * 16 + l15;
            float bval = __bfloat162float(bias[n]);
            int h = n >> 6, d = n & 63;
            for (int r = 0; r < 4; r++) {
                int mm = mbase + r;
                int b = mm >> 11, t = mm & 2047;
                float val = acc[mi][ni][r] + bval;
                size_t idx = (((size_t)b * HDIM + h) * TDIM + t) * DH + d;
                if (z == 0)      Qo[idx] = __float2bfloat16(val * 0.03125f);
                else if (z == 1) Ko[idx] = __float2bfloat16(val);
                else             Vo[idx] = __float2bfloat16(val);
            }
        }
    }
}

// ---------------------------------------------------------------------------
// Output projection: Y[M,K] @ WoT[N,K]^T + bo -> fp32 Out
// ---------------------------------------------------------------------------
__global__ __launch_bounds__(256) void proj_out_kernel(
    const bf16* __restrict__ X, const bf16* __restrict__ Bt,
    const bf16* __restrict__ bias, float* __restrict__ Out)
{
    __shared__ __align__(16) bf16 As[128 * 32];
    __shared__ __align__(16) bf16 Bs[128 * 32];

    const int tid  = threadIdx.x;
    const int lane = tid & 63;
    const int wave = tid >> 6;
    const int wr = wave >> 1, wc = wave & 1;
    const int l15 = lane & 15, quad = lane >> 4;

    const int blockM = blockIdx.y * 128;
    const int blockN = blockIdx.x * 128;

    f32x4 acc[4][4];
    for (int i = 0; i < 4; i++)
        for (int j = 0; j < 4; j++)
            acc[i][j] = (f32x4){0.f, 0.f, 0.f, 0.f};

    const int srow = lane >> 2, scol = (lane & 3) * 8;
    for (int k0 = 0; k0 < CDIM; k0 += 32) {
        for (int cc = 0; cc < 2; cc++) {
            int chunk = wave * 2 + cc;
            int row = chunk * 16 + srow;
            async_ld16(&X [(size_t)(blockM + row) * CDIM + k0 + scol], &As[chunk * 512]);
            async_ld16(&Bt[(size_t)(blockN + row) * CDIM + k0 + scol], &Bs[chunk * 512]);
        }
        __syncthreads();

        bf16x8 af[4], bfr[4];
        for (int mi = 0; mi < 4; mi++)
            af[mi] = *(const bf16x8*)&As[(wr * 64 + mi * 16 + l15) * 32 + quad * 8];
        for (int ni = 0; ni < 4; ni++)
            bfr[ni] = *(const bf16x8*)&Bs[(wc * 64 + ni * 16 + l15) * 32 + quad * 8];

        for (int mi = 0; mi < 4; mi++)
            for (int ni = 0; ni < 4; ni++)
                acc[mi][ni] = __builtin_amdgcn_mfma_f32_16x16x32_bf16(
                    af[mi], bfr[ni], acc[mi][ni], 0, 0, 0);
        __syncthreads();
    }

    for (int mi = 0; mi < 4; mi++) {
        int mbase = blockM + wr * 64 + mi * 16 + quad * 4;
        for (int ni = 0; ni < 4; ni++) {
            int n = blockN + wc * 64 + ni * 16 + l15;
            float bval = __bfloat162float(bias[n]);
            for (int r = 0; r < 4; r++)
                Out[(size_t)(mbase + r) * CDIM + n] = acc[mi][ni][r] + bval;
        }
    }
}

// ---------------------------------------------------------------------------
// Flash attention, causal.  Q-SPLIT + P-IN-REGISTERS + 128-q tiles.
// Block = 4 waves; each wave owns 32 q (two 16-q groups, g*64 apart) of a
// 128-row q-tile.  64-key K/V tiles staged once, fragments reused across both
// groups (halves LDS traffic/q vs 64-q tiles).  S^T = K.Q^T exits QK in
// [key=quad*4+r][q=l15] layout == B-operand of 16x16x16 MFMA -> exp in regs
// feeds PV directly, NO LDS round-trip for P (verified in round 8).
// Diagonal masking peeled to the last two iterations only.
// ---------------------------------------------------------------------------
__global__ __launch_bounds__(256, 4) void attn_kernel(
    const bf16* __restrict__ Q, const bf16* __restrict__ Kb,
    const bf16* __restrict__ Vt, bf16* __restrict__ Y)
{
    const int bh    = blockIdx.y;
    const int qT    = (int)gridDim.x - 1 - blockIdx.x;   // 0..15, heavy first
    const int qBase = qT * 128;
    const int tid  = threadIdx.x;
    const int lane = tid & 63, wave = tid >> 6;
    const int l15 = lane & 15, quad = lane >> 4;

    __shared__ __align__(16) bf16 Ks[64 * 72];       // [key][dh]
    __shared__ __align__(16) bf16 Vs[64 * 72];       // [dh][key]

    // Q B-fragments: group g rows = qBase + g*64 + wave*16 + l15
    bf16x8 qf[2][2];
    for (int g = 0; g < 2; g++) {
        const size_t qrow = (size_t)bh * TDIM + qBase + g * 64 + wave * 16 + l15;
        qf[g][0] = *(const bf16x8*)&Q[qrow * DH + quad * 8];
        qf[g][1] = *(const bf16x8*)&Q[qrow * DH + 32 + quad * 8];
    }

    // O^T accumulators: o[g][mt][r] -> d = mt*16+quad*4+r, q = l15
    f32x4 o[2][4];
    for (int g = 0; g < 2; g++)
        for (int mt = 0; mt < 4; mt++)
            o[g][mt] = (f32x4){0.f, 0.f, 0.f, 0.f};
    float lsum[2] = {0.f, 0.f};

    // staging coords: 256 threads x 2 chunks x 8 bf16 = 64x64 tile
    const int r0 = tid >> 3, kc0 = (tid & 7) * 8;

    const int nkt = 2 * qT + 2;
    uint4 kreg0 = *(const uint4*)&Kb[((size_t)bh * TDIM + r0) * DH + kc0];
    uint4 kreg1 = *(const uint4*)&Kb[((size_t)bh * TDIM + r0 + 32) * DH + kc0];
    uint4 vreg0 = *(const uint4*)&Vt[((size_t)bh * DH + r0) * TDIM + kc0];
    uint4 vreg1 = *(const uint4*)&Vt[((size_t)bh * DH + r0 + 32) * TDIM + kc0];

    for (int kt = 0; kt < nkt; kt++) {
        *(uint4*)&Ks[r0 * 72 + kc0]        = kreg0;
        *(uint4*)&Ks[(r0 + 32) * 72 + kc0] = kreg1;
        *(uint4*)&Vs[r0 * 72 + kc0]        = vreg0;
        *(uint4*)&Vs[(r0 + 32) * 72 + kc0] = vreg1;
        __syncthreads();

        if (kt + 1 < nkt) {
            const int nb = (kt + 1) * 64;
            kreg0 = *(const uint4*)&Kb[((size_t)bh * TDIM + nb + r0) * DH + kc0];
            kreg1 = *(const uint4*)&Kb[((size_t)bh * TDIM + nb + r0 + 32) * DH + kc0];
            vreg0 = *(const uint4*)&Vt[((size_t)bh * DH + r0) * TDIM + nb + kc0];
            vreg1 = *(const uint4*)&Vt[((size_t)bh * DH + r0 + 32) * TDIM + nb + kc0];
        }

        const int dg = kt - 2 * qT;   // <0: both full; 0: g0 diag; 1: g1 diag, g0 done
        for (int nt = 0; nt < 4; nt++) {
            // K A-frag for this 16-key chunk (shared across groups)
            bf16x8 kf0 = *(const bf16x8*)&Ks[(nt * 16 + l15) * 72 + quad * 8];
            bf16x8 kf1 = *(const bf16x8*)&Ks[(nt * 16 + l15) * 72 + 32 + quad * 8];
            // V A-frags (16x16x16): A[m=d mt*16+l15][k=key nt*16+quad*4+j]
            bf16x4 vA[4];
            for (int mt = 0; mt < 4; mt++)
                vA[mt] = *(const bf16x4*)&Vs[(mt * 16 + l15) * 72 + nt * 16 + quad * 4];

            for (int g = 0; g < 2; g++) {
                if (dg == 1 && g == 0) continue;      // group 0 causal range done
                f32x4 s = (f32x4){0.f, 0.f, 0.f, 0.f};
                s = __builtin_amdgcn_mfma_f32_16x16x32_bf16(kf0, qf[g][0], s, 0, 0, 0);
                s = __builtin_amdgcn_mfma_f32_16x16x32_bf16(kf1, qf[g][1], s, 0, 0, 0);

                const bool diag = (dg == g);
                bf16x4 pb;
                for (int r = 0; r < 4; r++) {
                    float pe = __expf(s[r]);
                    if (diag && (nt * 16 + quad * 4 + r > wave * 16 + l15)) pe = 0.f;
                    lsum[g] += pe;
                    pb[r] = (short)bf16bits(pe);
                }
                for (int mt = 0; mt < 4; mt++)
                    o[g][mt] = mfma_16x16x16_bf16(vA[mt], pb, o[g][mt]);
            }
        }
        __syncthreads();
    }

    // ---- epilogue: per group, normalize, LDS transpose, coalesced store ----
    const int b = bh >> 4, h = bh & 15;
    for (int g = 0; g < 2; g++) {
        float v = lsum[g];
        v += __shfl_xor(v, 16, 64);
        v += __shfl_xor(v, 32, 64);
        const float inv = 1.0f / v;

        // o -> LDS wave-private slice [q=l15 row][d col]  (reuse Ks)
        for (int mt = 0; mt < 4; mt++) {
            unsigned short pk[4];
            for (int r = 0; r < 4; r++) pk[r] = bf16bits(o[g][mt][r] * inv);
            *(ushort4*)&Ks[(wave * 16 + l15) * 72 + mt * 16 + quad * 4] = *(ushort4*)pk;
        }
        // same-wave readback, coalesced global store
        const int qq = lane >> 2, part = lane & 3;
        const int t = qBase + g * 64 + wave * 16 + qq;
        uint4 c0 = *(const uint4*)&Ks[(wave * 16 + qq) * 72 + part * 16];
        uint4 c1 = *(const uint4*)&Ks[(wave * 16 + qq) * 72 + part * 16 + 8];
        *(uint4*)&Y[((size_t)b * TDIM + t) * CDIM + h * DH + part * 16]     = c0;
        *(uint4*)&Y[((size_t)b * TDIM + t) * CDIM + h * DH + part * 16 + 8] = c1;
    }
}

// ---------------------------------------------------------------------------
extern "C" void kernel_launch(void* const* d_in, const int* in_sizes, int n_in,
                              void* d_out, int out_size, void* d_ws, size_t ws_size,
                              hipStream_t stream) {
    (void)in_sizes; (void)n_in; (void)out_size; (void)ws_size;

    char* ws = (char*)d_ws;
    const size_t SZ_BHTD = (size_t)BDIM * HDIM * TDIM * DH * sizeof(bf16);  // 16 MiB
    const size_t SZ_W    = (size_t)HDIM * CDIM * DH * sizeof(bf16);         // 2 MiB
    bf16* Qb  = (bf16*)(ws);
    bf16* Kb  = (bf16*)(ws + SZ_BHTD);
    bf16* Vt  = (bf16*)(ws + 2 * SZ_BHTD);
    bf16* Y   = (bf16*)(ws + 3 * SZ_BHTD);
    bf16* WqT = (bf16*)(ws + 4 * SZ_BHTD);
    bf16* WkT = (bf16*)(ws + 4 * SZ_BHTD + SZ_W);
    bf16* WvT = (bf16*)(ws + 4 * SZ_BHTD + 2 * SZ_W);
    bf16* WoT = (bf16*)(ws + 4 * SZ_BHTD + 3 * SZ_W);
    bf16* xC  = (bf16*)(ws + 4 * SZ_BHTD + 4 * SZ_W);                       // 16 MiB
    bf16* bqC = (bf16*)(ws + 5 * SZ_BHTD + 4 * SZ_W);
    bf16* bkC = bqC + 1024;
    bf16* bvC = bqC + 2048;
    bf16* boC = bqC + 3072;
    bf16* Vb  = (bf16*)d_out;   // scratch: V [bh][t][d] lives in d_out until proj_out

    const int nX4 = (BDIM * TDIM * CDIM) / 4;
    convert_x4<<<nX4 / 256, 256, 0, stream>>>((const float4*)d_in[0], (ushort4*)xC, nX4);
    convert_biases<<<16, 256, 0, stream>>>((const float*)d_in[2], (const float*)d_in[4],
                                           (const float*)d_in[6], (const float*)d_in[8], bqC);

    transpose_qkv_kernel<<<dim3(CDIM / 64, 1, 48), 256, 0, stream>>>(
        (const float*)d_in[1], (const float*)d_in[3], (const float*)d_in[5], WqT, WkT, WvT);
    transpose_wo_kernel<<<dim3(CDIM / 64, CDIM / 64), 256, 0, stream>>>(
        (const float*)d_in[7], WoT);

    dim3 gq(CDIM / 128, (BDIM * TDIM) / 128, 3);
    proj_qkv_kernel<<<gq, 256, 0, stream>>>(xC, WqT, WkT, WvT, bqC, bkC, bvC, Qb, Kb, Vb);

    transpose_v_kernel<<<dim3(TDIM / 64, BDIM * HDIM), 256, 0, stream>>>(Vb, Vt);

    attn_kernel<<<dim3(TDIM / 128, BDIM * HDIM), 256, 0, stream>>>(Qb, Kb, Vt, Y);

    proj_out_kernel<<<dim3(CDIM / 128, (BDIM * TDIM) / 128), 256, 0, stream>>>(
        Y, WoT, boC, (float*)d_out);
}